// Round 5
// baseline (3033.157 us; speedup 1.0000x reference)
//
#include <hip/hip_runtime.h>
#include <hip/hip_bf16.h>

#define N_NODES 100000
#define EMB 256
#define HID 64
#define N_REL 5
#define N_EDGES 3200000
#define BATCH 16384
#define NB 782                 // buckets of 128 dst nodes
#define NWG1 256               // scatter/hist WGs
#define CH 12500               // edges per WG chunk (256*12500 = 3.2M exact)
#define LSEG 640               // 128 nodes * 5 rels

typedef unsigned short u16;
typedef unsigned int u32;
typedef __attribute__((ext_vector_type(4))) float f32x4;
typedef __attribute__((ext_vector_type(8))) short short8;

__device__ __forceinline__ float bf2f(u16 u) {
    union { float f; u32 i; } v;
    v.i = ((u32)u) << 16;
    return v.f;
}
__device__ __forceinline__ u16 f2bf(float f) {
    union { float f; u32 i; } v;
    v.f = f;
    u32 r = v.i + 0x7fff + ((v.i >> 16) & 1);   // RNE
    return (u16)(r >> 16);
}

__device__ __forceinline__ void gload_lds16(const void* g, void* l) {
    __builtin_amdgcn_global_load_lds(
        (const __attribute__((address_space(1))) unsigned int*)g,
        (__attribute__((address_space(3))) unsigned int*)l, 16, 0, 0);
}

// ---------------------------------------------------------------------------
// K1: per-WG bucket histogram (deterministic chunks, no global atomics)
// ---------------------------------------------------------------------------
__global__ __launch_bounds__(256) void bucket_hist(const int* __restrict__ dst,
                                                   int* __restrict__ hist) {
    __shared__ int hl[NB];
    const int tid = threadIdx.x;
    for (int i = tid; i < NB; i += 256) hl[i] = 0;
    __syncthreads();
    const int w = blockIdx.x;
    const int s = w * CH, e = s + CH;
    for (int i = s + tid; i < e; i += 256)
        atomicAdd(&hl[dst[i] >> 7], 1);
    __syncthreads();
    for (int i = tid; i < NB; i += 256) hist[w * NB + i] = hl[i];
}

// ---------------------------------------------------------------------------
// K2a: per-bucket column scan over WGs (in-place hist -> base_local), btot out
// ---------------------------------------------------------------------------
__global__ void col_scan(int* __restrict__ hist, int* __restrict__ btot) {
    const int b = blockIdx.x;
    const int lane = threadIdx.x;
    int carry = 0;
    for (int c = 0; c < NWG1; c += 64) {
        int v = hist[(c + lane) * NB + b];
        int incl = v;
#pragma unroll
        for (int off = 1; off < 64; off <<= 1) {
            int t = __shfl_up(incl, off);
            if (lane >= off) incl += t;
        }
        hist[(c + lane) * NB + b] = carry + (incl - v);
        carry += __shfl(incl, 63);
    }
    if (lane == 0) btot[b] = carry;
}

// ---------------------------------------------------------------------------
// K2b: scan bucket totals -> bucket offsets (+ sentinel)
// ---------------------------------------------------------------------------
__global__ void btot_scan(const int* __restrict__ btot, int* __restrict__ boffs) {
    const int lane = threadIdx.x;
    int carry = 0;
    for (int c = 0; c < NB; c += 64) {
        int v = (c + lane < NB) ? btot[c + lane] : 0;
        int incl = v;
#pragma unroll
        for (int off = 1; off < 64; off <<= 1) {
            int t = __shfl_up(incl, off);
            if (lane >= off) incl += t;
        }
        if (c + lane < NB) boffs[c + lane] = carry + (incl - v);
        carry += __shfl(incl, 63);
    }
    if (lane == 0) boffs[NB] = N_EDGES;
}

// ---------------------------------------------------------------------------
// K3: scatter packed keys into bucket-ordered array (LDS cursors -> bursts)
// key = src | ((ldst*5 + et) << 17)
// ---------------------------------------------------------------------------
__global__ __launch_bounds__(256) void bucket_scatter(
        const int* __restrict__ src, const int* __restrict__ dst,
        const int* __restrict__ et, const int* __restrict__ base,
        const int* __restrict__ boffs, u32* __restrict__ bucketed) {
    __shared__ int cur[NB];
    const int tid = threadIdx.x;
    const int w = blockIdx.x;
    for (int i = tid; i < NB; i += 256) cur[i] = boffs[i] + base[w * NB + i];
    __syncthreads();
    const int s = w * CH, e = s + CH;
    for (int i = s + tid; i < e; i += 256) {
        int d = dst[i];
        int b = d >> 7;
        u32 key = (u32)src[i] | ((u32)((d & 127) * 5 + et[i]) << 17);
        int pos = atomicAdd(&cur[b], 1);
        bucketed[pos] = key;
    }
}

// ---------------------------------------------------------------------------
// Pack weights: BT[j][k] = (j<320 ? W[j>>6][k][j&63] : root[k][j&63]) as bf16
// ---------------------------------------------------------------------------
__global__ void build_bt(const float* __restrict__ W, const float* __restrict__ root,
                         int K, u16* __restrict__ BT) {
    int idx = blockIdx.x * blockDim.x + threadIdx.x;
    if (idx >= 384 * K) return;
    int j = idx / K, k = idx - j * K;
    float v = (j < 320) ? W[((j >> 6) * K + k) * 64 + (j & 63)]
                        : root[k * 64 + (j & 63)];
    BT[idx] = f2bf(v);
}

// ---------------------------------------------------------------------------
// MFMA GEMM: C[100000][384](bf16) = A[100000][K] x BT[384][K]^T
// (unchanged from round 4 — verified correct)
// ---------------------------------------------------------------------------
template <int K, bool A_F32>
__global__ __launch_bounds__(256) void mfma_gemm(
        const void* __restrict__ Av, const u16* __restrict__ BT,
        u16* __restrict__ C) {
    __shared__ __align__(16) u16 Al[128 * 64];
    __shared__ __align__(16) u16 Bl[128 * 64];
    const int tid  = threadIdx.x;
    const int lane = tid & 63;
    const int wave = tid >> 6;
    const int m0 = blockIdx.x * 128;
    const int n0 = blockIdx.y * 128;
    const int wr = (wave >> 1) * 64;
    const int wc = (wave & 1) * 64;
    const int l15 = lane & 15;
    const int lg  = lane >> 4;

    f32x4 acc[4][4];
#pragma unroll
    for (int i = 0; i < 4; ++i)
#pragma unroll
        for (int j = 0; j < 4; ++j) {
            f32x4 z = {0.f, 0.f, 0.f, 0.f};
            acc[i][j] = z;
        }

    for (int k0 = 0; k0 < K; k0 += 64) {
#pragma unroll
        for (int i = 0; i < 4; ++i) {
            int c = wave * 4 + i;
            int row = c * 8 + (lane >> 3);
            int kk  = (lane & 7) * 8;
            gload_lds16(BT + (size_t)(n0 + row) * K + k0 + kk, &Bl[c * 512]);
        }
        if (A_F32) {
            const float* Af = (const float*)Av;
#pragma unroll
            for (int p = 0; p < 8; ++p) {
                int f = p * 1024 + tid * 4;
                int row = f >> 6;
                int col = f & 63;
                int gr = m0 + row;
                if (gr > N_NODES - 1) gr = N_NODES - 1;
                float4 v = *(const float4*)(Af + (size_t)gr * K + k0 + col);
                ushort4 o;
                o.x = f2bf(v.x); o.y = f2bf(v.y); o.z = f2bf(v.z); o.w = f2bf(v.w);
                *(ushort4*)&Al[row * 64 + col] = o;
            }
        } else {
            const u16* Ab = (const u16*)Av;
#pragma unroll
            for (int i = 0; i < 4; ++i) {
                int c = wave * 4 + i;
                int row = c * 8 + (lane >> 3);
                int kk  = (lane & 7) * 8;
                gload_lds16(Ab + (size_t)(m0 + row) * K + k0 + kk, &Al[c * 512]);
            }
        }
        __syncthreads();

#pragma unroll
        for (int kk = 0; kk < 64; kk += 32) {
            short8 af[4], bf[4];
#pragma unroll
            for (int f = 0; f < 4; ++f) {
                af[f] = *(const short8*)&Al[(wr + f * 16 + l15) * 64 + kk + lg * 8];
                bf[f] = *(const short8*)&Bl[(wc + f * 16 + l15) * 64 + kk + lg * 8];
            }
#pragma unroll
            for (int fm = 0; fm < 4; ++fm)
#pragma unroll
                for (int fn = 0; fn < 4; ++fn)
                    acc[fm][fn] = __builtin_amdgcn_mfma_f32_16x16x32_bf16(
                        af[fm], bf[fn], acc[fm][fn], 0, 0, 0);
        }
        __syncthreads();
    }

#pragma unroll
    for (int fm = 0; fm < 4; ++fm) {
        int rbase = m0 + wr + fm * 16 + lg * 4;
#pragma unroll
        for (int i = 0; i < 4; ++i) {
            int r = rbase + i;
            if (r < N_NODES) {
#pragma unroll
                for (int fn = 0; fn < 4; ++fn)
                    C[(size_t)r * 384 + n0 + wc + fn * 16 + l15] = f2bf(acc[fm][fn][i]);
            }
        }
    }
}

// ---------------------------------------------------------------------------
// Fused aggregate: one WG per bucket (128 dst nodes).
// Pass A: LDS seg histogram -> inv. Pass B: wave-per-edge gather + ds_add_f32.
// Epilogue: + root slice + bias (+relu), bf16 out.
// ---------------------------------------------------------------------------
template <bool RELU>
__global__ __launch_bounds__(256) void agg_fused(
        const u16* __restrict__ h, const u32* __restrict__ keys,
        const int* __restrict__ boffs, const float* __restrict__ bias,
        u16* __restrict__ out) {
    __shared__ float acc[128 * 64];   // 32 KB
    __shared__ float invw[LSEG];      // 2.5 KB (int during histogram)
    const int tid = threadIdx.x;
    const int b = blockIdx.x;
    const int nb0 = b << 7;
    const int nn = min(128, N_NODES - nb0);
    const int s = boffs[b], e = boffs[b + 1];

    for (int i = tid; i < 128 * 64; i += 256) acc[i] = 0.f;
    int* cntl = (int*)invw;
    for (int i = tid; i < LSEG; i += 256) cntl[i] = 0;
    __syncthreads();

    for (int i = s + tid; i < e; i += 256)
        atomicAdd(&cntl[keys[i] >> 17], 1);
    __syncthreads();
    for (int i = tid; i < LSEG; i += 256) {
        int c = cntl[i];
        invw[i] = 1.0f / (float)max(c, 1);
    }
    __syncthreads();

    const int lane = tid & 63;
    const int wv = tid >> 6;
    for (int base = s + wv * 8; base < e; base += 32) {
#pragma unroll
        for (int j = 0; j < 8; ++j) {
            int i = base + j;
            if (i < e) {
                u32 key = keys[i];                      // uniform -> broadcast
                u32 srcn = key & 0x1FFFF;
                u32 lseg = key >> 17;
                u32 q = (lseg * 52429u) >> 18;          // lseg / 5
                u32 rel = lseg - q * 5u;
                float wgt = invw[lseg];
                float v = bf2f(h[(size_t)srcn * 384 + rel * 64 + lane]);
                atomicAdd(&acc[q * 64 + lane], v * wgt);
            }
        }
    }
    __syncthreads();

    const float bl = bias[lane];
    for (int r = wv; r < nn; r += 4) {
        float val = acc[r * 64 + lane] + bf2f(h[(size_t)(nb0 + r) * 384 + 320 + lane]) + bl;
        if (RELU) val = fmaxf(val, 0.f);
        out[(size_t)(nb0 + r) * 64 + lane] = f2bf(val);
    }
}

// ---------------------------------------------------------------------------
// Merge MLP + BCE/accuracy (nodes in bf16)
// ---------------------------------------------------------------------------
__global__ __launch_bounds__(256) void loss_kernel(
        const u16* __restrict__ nodes, const int* __restrict__ bill,
        const int* __restrict__ u1, const int* __restrict__ u2,
        const float* __restrict__ w1, const float* __restrict__ b1,
        const float* __restrict__ w2, const float* __restrict__ b2,
        float* __restrict__ out) {
    __shared__ float Wl[128 * 64];
    __shared__ float red[2][4];
    for (int j = threadIdx.x; j < 128 * 16; j += 256)
        ((float4*)Wl)[j] = ((const float4*)w1)[j];
    __syncthreads();

    const int lane = threadIdx.x & 63;
    const int wv   = threadIdx.x >> 6;
    const int gw   = blockIdx.x * 4 + wv;
    const int nw   = gridDim.x * 4;

    const float bias1 = b1[lane];
    const float w2l   = w2[lane];
    const float bias2 = b2[0];

    float bce_acc = 0.f, corr_acc = 0.f;
    for (int s = gw; s < BATCH; s += nw) {
        const u16* xb  = nodes + (size_t)bill[s] * 64;
        const u16* xu1 = nodes + (size_t)u1[s] * 64;
        const u16* xu2 = nodes + (size_t)u2[s] * 64;
        float hb = bias1, h1 = 0.f, h2 = 0.f;
#pragma unroll 8
        for (int i = 0; i < 64; ++i) {
            float wb = Wl[i * 64 + lane];
            float wu = Wl[(64 + i) * 64 + lane];
            hb += bf2f(xb[i]) * wb;
            h1 += bf2f(xu1[i]) * wu;
            h2 += bf2f(xu2[i]) * wu;
        }
        float p1 = fmaxf(hb + h1, 0.f) * w2l;
        float p2 = fmaxf(hb + h2, 0.f) * w2l;
#pragma unroll
        for (int off = 32; off > 0; off >>= 1) {
            p1 += __shfl_down(p1, off);
            p2 += __shfl_down(p2, off);
        }
        if (lane == 0) {
            float z1 = p1 + bias2;   // target 1
            float z2 = p2 + bias2;   // target 0
            bce_acc += fmaxf(z1, 0.f) - z1 + log1pf(expf(-fabsf(z1)));
            bce_acc += fmaxf(z2, 0.f)      + log1pf(expf(-fabsf(z2)));
            corr_acc += (z1 > 0.f) ? 1.f : 0.f;
            corr_acc += (z2 > 0.f) ? 0.f : 1.f;
        }
    }
    if (lane == 0) { red[0][wv] = bce_acc; red[1][wv] = corr_acc; }
    __syncthreads();
    if (threadIdx.x == 0) {
        const float scale = 1.f / (2.f * BATCH);
        atomicAdd(&out[0], (red[0][0] + red[0][1] + red[0][2] + red[0][3]) * scale);
        atomicAdd(&out[1], (red[1][0] + red[1][1] + red[1][2] + red[1][3]) * scale);
    }
}

// ---------------------------------------------------------------------------
extern "C" void kernel_launch(void* const* d_in, const int* in_sizes, int n_in,
                              void* d_out, int out_size, void* d_ws, size_t ws_size,
                              hipStream_t stream) {
    const int*   bill  = (const int*)d_in[0];
    const int*   u1    = (const int*)d_in[1];
    const int*   u2    = (const int*)d_in[2];
    const int*   ei    = (const int*)d_in[3];
    const int*   et    = (const int*)d_in[4];
    const float* uf    = (const float*)d_in[5];
    const float* W1    = (const float*)d_in[6];
    const float* root1 = (const float*)d_in[7];
    const float* b1    = (const float*)d_in[8];
    const float* W2    = (const float*)d_in[9];
    const float* root2 = (const float*)d_in[10];
    const float* b2    = (const float*)d_in[11];
    const float* m1w   = (const float*)d_in[12];
    const float* m1b   = (const float*)d_in[13];
    const float* m2w   = (const float*)d_in[14];
    const float* m2b   = (const float*)d_in[15];
    float* out = (float*)d_out;

    // ws layout (peak 103,452,800 B < proven 106,400,000 B):
    //   0           h_all     76,800,000   [100000][384] bf16
    //  76,800,000   bucketed  12,800,000   u32 keys, bucket-ordered
    //  89,600,000   xbuf      12,800,000   (+12,288 B read-only slop into hist: OK)
    // 102,400,000   hist/base    800,768   [256][782] int
    // 103,200,768   btot           3,128
    // 103,203,896   boffs          3,132   (783 ints)
    // 103,207,040   BT1          196,608   (16B aligned)
    // 103,403,648   BT2           49,152
    char* ws = (char*)d_ws;
    u16* h_all    = (u16*)(ws);
    u32* bucketed = (u32*)(ws + 76800000);
    u16* xbuf     = (u16*)(ws + 89600000);
    int* hist     = (int*)(ws + 102400000);
    int* btot     = (int*)(ws + 103200768);
    int* boffs    = (int*)(ws + 103203896);
    u16* BT1      = (u16*)(ws + 103207040);
    u16* BT2      = (u16*)(ws + 103403648);
    if (ws_size < 103452800) return;  // fail visibly

    const int* src = ei;
    const int* dst = ei + N_EDGES;

    hipMemsetAsync(d_out, 0, 2 * sizeof(float), stream);

    // ---- bucket sort (coarse only) + offsets
    bucket_hist<<<NWG1, 256, 0, stream>>>(dst, hist);
    col_scan<<<NB, 64, 0, stream>>>(hist, btot);
    btot_scan<<<1, 64, 0, stream>>>(btot, boffs);
    bucket_scatter<<<NWG1, 256, 0, stream>>>(src, dst, et, hist, boffs, bucketed);

    // ---- pack weights to BT (bf16, [384][K])
    build_bt<<<(384 * EMB + 255) / 256, 256, 0, stream>>>(W1, root1, EMB, BT1);
    build_bt<<<(384 * HID + 255) / 256, 256, 0, stream>>>(W2, root2, HID, BT2);

    // ---- Layer 1
    mfma_gemm<EMB, true><<<dim3(782, 3), 256, 0, stream>>>(uf, BT1, h_all);
    agg_fused<true><<<NB, 256, 0, stream>>>(h_all, bucketed, boffs, b1, xbuf);

    // ---- Layer 2
    mfma_gemm<HID, false><<<dim3(782, 3), 256, 0, stream>>>(xbuf, BT2, h_all);
    agg_fused<false><<<NB, 256, 0, stream>>>(h_all, bucketed, boffs, b2, xbuf);

    // ---- Merge MLP + BCE + accuracy
    loss_kernel<<<128, 256, 0, stream>>>(xbuf, bill, u1, u2, m1w, m1b, m2w, m2b, out);
}

// Round 6
// 902.752 us; speedup vs baseline: 3.3599x; 3.3599x over previous
//
#include <hip/hip_runtime.h>
#include <hip/hip_bf16.h>

#define N_NODES 100000
#define EMB 256
#define HID 64
#define N_REL 5
#define N_EDGES 3200000
#define BATCH 16384
#define NB 782                 // buckets of 128 dst nodes
#define NWG1 256               // scatter/hist WGs
#define CH 12500               // edges per WG chunk (256*12500 = 3.2M exact)
#define LSEG 640               // 128 nodes * 5 rels
#define NSEG (N_NODES * N_REL) // 500000

typedef unsigned short u16;
typedef unsigned int u32;
typedef __attribute__((ext_vector_type(4))) float f32x4;
typedef __attribute__((ext_vector_type(8))) short short8;

__device__ __forceinline__ float bf2f(u16 u) {
    union { float f; u32 i; } v;
    v.i = ((u32)u) << 16;
    return v.f;
}
__device__ __forceinline__ u16 f2bf(float f) {
    union { float f; u32 i; } v;
    v.f = f;
    u32 r = v.i + 0x7fff + ((v.i >> 16) & 1);   // RNE
    return (u16)(r >> 16);
}

__device__ __forceinline__ void gload_lds16(const void* g, void* l) {
    __builtin_amdgcn_global_load_lds(
        (const __attribute__((address_space(1))) unsigned int*)g,
        (__attribute__((address_space(3))) unsigned int*)l, 16, 0, 0);
}

// ---------------------------------------------------------------------------
// K1: per-WG bucket histogram (deterministic chunks, no global atomics)
// ---------------------------------------------------------------------------
__global__ __launch_bounds__(256) void bucket_hist(const int* __restrict__ dst,
                                                   int* __restrict__ hist) {
    __shared__ int hl[NB];
    const int tid = threadIdx.x;
    for (int i = tid; i < NB; i += 256) hl[i] = 0;
    __syncthreads();
    const int w = blockIdx.x;
    const int s = w * CH, e = s + CH;
    for (int i = s + tid; i < e; i += 256)
        atomicAdd(&hl[dst[i] >> 7], 1);
    __syncthreads();
    for (int i = tid; i < NB; i += 256) hist[w * NB + i] = hl[i];
}

// ---------------------------------------------------------------------------
// K2a: per-bucket column scan over WGs (in-place hist -> base_local), btot out
// ---------------------------------------------------------------------------
__global__ void col_scan(int* __restrict__ hist, int* __restrict__ btot) {
    const int b = blockIdx.x;
    const int lane = threadIdx.x;
    int carry = 0;
    for (int c = 0; c < NWG1; c += 64) {
        int v = hist[(c + lane) * NB + b];
        int incl = v;
#pragma unroll
        for (int off = 1; off < 64; off <<= 1) {
            int t = __shfl_up(incl, off);
            if (lane >= off) incl += t;
        }
        hist[(c + lane) * NB + b] = carry + (incl - v);
        carry += __shfl(incl, 63);
    }
    if (lane == 0) btot[b] = carry;
}

// ---------------------------------------------------------------------------
// K2b: scan bucket totals -> bucket offsets (+ sentinels)
// ---------------------------------------------------------------------------
__global__ void btot_scan(const int* __restrict__ btot, int* __restrict__ boffs,
                          int* __restrict__ offs) {
    const int lane = threadIdx.x;
    int carry = 0;
    for (int c = 0; c < NB; c += 64) {
        int v = (c + lane < NB) ? btot[c + lane] : 0;
        int incl = v;
#pragma unroll
        for (int off = 1; off < 64; off <<= 1) {
            int t = __shfl_up(incl, off);
            if (lane >= off) incl += t;
        }
        if (c + lane < NB) boffs[c + lane] = carry + (incl - v);
        carry += __shfl(incl, 63);
    }
    if (lane == 0) {
        boffs[NB] = N_EDGES;
        offs[NSEG] = N_EDGES;   // global sentinel for offs-diff degree
    }
}

// ---------------------------------------------------------------------------
// K3: scatter packed keys into bucket-ordered array (LDS cursors -> bursts)
// key = src | ((ldst*5 + et) << 17)
// ---------------------------------------------------------------------------
__global__ __launch_bounds__(256) void bucket_scatter(
        const int* __restrict__ src, const int* __restrict__ dst,
        const int* __restrict__ et, const int* __restrict__ base,
        const int* __restrict__ boffs, u32* __restrict__ bucketed) {
    __shared__ int cur[NB];
    const int tid = threadIdx.x;
    const int w = blockIdx.x;
    for (int i = tid; i < NB; i += 256) cur[i] = boffs[i] + base[w * NB + i];
    __syncthreads();
    const int s = w * CH, e = s + CH;
    for (int i = s + tid; i < e; i += 256) {
        int d = dst[i];
        int b = d >> 7;
        u32 key = (u32)src[i] | ((u32)((d & 127) * 5 + et[i]) << 17);
        int pos = atomicAdd(&cur[b], 1);
        bucketed[pos] = key;
    }
}

// ---------------------------------------------------------------------------
// K4: within-bucket segment sort. One WG per bucket: LDS histogram of 640
// local segs -> wave scan -> global offs + LDS-cursor scatter of keys.
// ---------------------------------------------------------------------------
__global__ __launch_bounds__(256) void seg_sort(
        const u32* __restrict__ keys, const int* __restrict__ boffs,
        int* __restrict__ offs, u32* __restrict__ sorted) {
    __shared__ int cntl[LSEG];
    __shared__ int cur[LSEG];
    const int tid = threadIdx.x;
    const int b = blockIdx.x;
    const int s = boffs[b], e = boffs[b + 1];

    for (int i = tid; i < LSEG; i += 256) cntl[i] = 0;
    __syncthreads();
    for (int i = s + tid; i < e; i += 256)
        atomicAdd(&cntl[keys[i] >> 17], 1);
    __syncthreads();

    if (tid < 64) {   // wave 0: exclusive scan of 640 counts
        int carry = 0;
        for (int c = 0; c < LSEG; c += 64) {
            int v = cntl[c + tid];
            int incl = v;
#pragma unroll
            for (int off = 1; off < 64; off <<= 1) {
                int t = __shfl_up(incl, off);
                if (tid >= off) incl += t;
            }
            cur[c + tid] = carry + (incl - v);
            carry += __shfl(incl, 63);
        }
    }
    __syncthreads();

    const int segbase = b * LSEG;   // == (b*128)*5
    for (int i = tid; i < LSEG; i += 256)
        if (segbase + i < NSEG) offs[segbase + i] = s + cur[i];
    __syncthreads();

    for (int i = s + tid; i < e; i += 256) {
        u32 key = keys[i];
        int pos = s + atomicAdd(&cur[key >> 17], 1);
        sorted[pos] = key;
    }
}

// ---------------------------------------------------------------------------
// Pack weights: BT[j][k] = (j<320 ? W[j>>6][k][j&63] : root[k][j&63]) as bf16
// ---------------------------------------------------------------------------
__global__ void build_bt(const float* __restrict__ W, const float* __restrict__ root,
                         int K, u16* __restrict__ BT) {
    int idx = blockIdx.x * blockDim.x + threadIdx.x;
    if (idx >= 384 * K) return;
    int j = idx / K, k = idx - j * K;
    float v = (j < 320) ? W[((j >> 6) * K + k) * 64 + (j & 63)]
                        : root[k * 64 + (j & 63)];
    BT[idx] = f2bf(v);
}

// ---------------------------------------------------------------------------
// MFMA GEMM: C[100000][384](bf16) = A[100000][K] x BT[384][K]^T
// (unchanged from round 4 — verified correct)
// ---------------------------------------------------------------------------
template <int K, bool A_F32>
__global__ __launch_bounds__(256) void mfma_gemm(
        const void* __restrict__ Av, const u16* __restrict__ BT,
        u16* __restrict__ C) {
    __shared__ __align__(16) u16 Al[128 * 64];
    __shared__ __align__(16) u16 Bl[128 * 64];
    const int tid  = threadIdx.x;
    const int lane = tid & 63;
    const int wave = tid >> 6;
    const int m0 = blockIdx.x * 128;
    const int n0 = blockIdx.y * 128;
    const int wr = (wave >> 1) * 64;
    const int wc = (wave & 1) * 64;
    const int l15 = lane & 15;
    const int lg  = lane >> 4;

    f32x4 acc[4][4];
#pragma unroll
    for (int i = 0; i < 4; ++i)
#pragma unroll
        for (int j = 0; j < 4; ++j) {
            f32x4 z = {0.f, 0.f, 0.f, 0.f};
            acc[i][j] = z;
        }

    for (int k0 = 0; k0 < K; k0 += 64) {
#pragma unroll
        for (int i = 0; i < 4; ++i) {
            int c = wave * 4 + i;
            int row = c * 8 + (lane >> 3);
            int kk  = (lane & 7) * 8;
            gload_lds16(BT + (size_t)(n0 + row) * K + k0 + kk, &Bl[c * 512]);
        }
        if (A_F32) {
            const float* Af = (const float*)Av;
#pragma unroll
            for (int p = 0; p < 8; ++p) {
                int f = p * 1024 + tid * 4;
                int row = f >> 6;
                int col = f & 63;
                int gr = m0 + row;
                if (gr > N_NODES - 1) gr = N_NODES - 1;
                float4 v = *(const float4*)(Af + (size_t)gr * K + k0 + col);
                ushort4 o;
                o.x = f2bf(v.x); o.y = f2bf(v.y); o.z = f2bf(v.z); o.w = f2bf(v.w);
                *(ushort4*)&Al[row * 64 + col] = o;
            }
        } else {
            const u16* Ab = (const u16*)Av;
#pragma unroll
            for (int i = 0; i < 4; ++i) {
                int c = wave * 4 + i;
                int row = c * 8 + (lane >> 3);
                int kk  = (lane & 7) * 8;
                gload_lds16(Ab + (size_t)(m0 + row) * K + k0 + kk, &Al[c * 512]);
            }
        }
        __syncthreads();

#pragma unroll
        for (int kk = 0; kk < 64; kk += 32) {
            short8 af[4], bf[4];
#pragma unroll
            for (int f = 0; f < 4; ++f) {
                af[f] = *(const short8*)&Al[(wr + f * 16 + l15) * 64 + kk + lg * 8];
                bf[f] = *(const short8*)&Bl[(wc + f * 16 + l15) * 64 + kk + lg * 8];
            }
#pragma unroll
            for (int fm = 0; fm < 4; ++fm)
#pragma unroll
                for (int fn = 0; fn < 4; ++fn)
                    acc[fm][fn] = __builtin_amdgcn_mfma_f32_16x16x32_bf16(
                        af[fm], bf[fn], acc[fm][fn], 0, 0, 0);
        }
        __syncthreads();
    }

#pragma unroll
    for (int fm = 0; fm < 4; ++fm) {
        int rbase = m0 + wr + fm * 16 + lg * 4;
#pragma unroll
        for (int i = 0; i < 4; ++i) {
            int r = rbase + i;
            if (r < N_NODES) {
#pragma unroll
                for (int fn = 0; fn < 4; ++fn)
                    C[(size_t)r * 384 + n0 + wc + fn * 16 + l15] = f2bf(acc[fm][fn][i]);
            }
        }
    }
}

// ---------------------------------------------------------------------------
// Aggregate (flattened): one wave per dst node, lane = feature.
// Node's 5 segments are contiguous in sorted[]; single loop over the node's
// degree with 8 outstanding gathers; per-rel mean weight via cndmask select.
// ---------------------------------------------------------------------------
template <bool RELU>
__global__ __launch_bounds__(256) void agg_flat(
        const u16* __restrict__ h, const u32* __restrict__ skeys,
        const int* __restrict__ offs, const float* __restrict__ bias,
        u16* __restrict__ out) {
    const int lane = threadIdx.x & 63;
    const int d = (blockIdx.x * blockDim.x + threadIdx.x) >> 6;
    if (d >= N_NODES) return;

    int o0 = offs[d * 5 + 0], o1 = offs[d * 5 + 1], o2 = offs[d * 5 + 2];
    int o3 = offs[d * 5 + 3], o4 = offs[d * 5 + 4], o5 = offs[d * 5 + 5];
    float i0 = 1.f / (float)max(o1 - o0, 1);
    float i1 = 1.f / (float)max(o2 - o1, 1);
    float i2 = 1.f / (float)max(o3 - o2, 1);
    float i3 = 1.f / (float)max(o4 - o3, 1);
    float i4 = 1.f / (float)max(o5 - o4, 1);

    float acc = bf2f(h[(size_t)d * 384 + 320 + lane]) + bias[lane];
    const int deg = o5 - o0;
    for (int k = 0; k < deg; k += 8) {
#pragma unroll
        for (int j = 0; j < 8; ++j) {
            if (k + j < deg) {
                u32 key = skeys[o0 + k + j];            // uniform -> broadcast
                u32 srcn = key & 0x1FFFF;
                u32 lseg = key >> 17;
                u32 q = (lseg * 52429u) >> 18;          // lseg / 5
                u32 rel = lseg - q * 5u;
                float w = rel == 0 ? i0 : rel == 1 ? i1 : rel == 2 ? i2
                        : rel == 3 ? i3 : i4;
                acc += bf2f(h[(size_t)srcn * 384 + rel * 64 + lane]) * w;
            }
        }
    }
    if (RELU) acc = fmaxf(acc, 0.f);
    out[(size_t)d * 64 + lane] = f2bf(acc);
}

// ---------------------------------------------------------------------------
// Merge MLP + BCE/accuracy (nodes in bf16)
// ---------------------------------------------------------------------------
__global__ __launch_bounds__(256) void loss_kernel(
        const u16* __restrict__ nodes, const int* __restrict__ bill,
        const int* __restrict__ u1, const int* __restrict__ u2,
        const float* __restrict__ w1, const float* __restrict__ b1,
        const float* __restrict__ w2, const float* __restrict__ b2,
        float* __restrict__ out) {
    __shared__ float Wl[128 * 64];
    __shared__ float red[2][4];
    for (int j = threadIdx.x; j < 128 * 16; j += 256)
        ((float4*)Wl)[j] = ((const float4*)w1)[j];
    __syncthreads();

    const int lane = threadIdx.x & 63;
    const int wv   = threadIdx.x >> 6;
    const int gw   = blockIdx.x * 4 + wv;
    const int nw   = gridDim.x * 4;

    const float bias1 = b1[lane];
    const float w2l   = w2[lane];
    const float bias2 = b2[0];

    float bce_acc = 0.f, corr_acc = 0.f;
    for (int s = gw; s < BATCH; s += nw) {
        const u16* xb  = nodes + (size_t)bill[s] * 64;
        const u16* xu1 = nodes + (size_t)u1[s] * 64;
        const u16* xu2 = nodes + (size_t)u2[s] * 64;
        float hb = bias1, h1 = 0.f, h2 = 0.f;
#pragma unroll 8
        for (int i = 0; i < 64; ++i) {
            float wb = Wl[i * 64 + lane];
            float wu = Wl[(64 + i) * 64 + lane];
            hb += bf2f(xb[i]) * wb;
            h1 += bf2f(xu1[i]) * wu;
            h2 += bf2f(xu2[i]) * wu;
        }
        float p1 = fmaxf(hb + h1, 0.f) * w2l;
        float p2 = fmaxf(hb + h2, 0.f) * w2l;
#pragma unroll
        for (int off = 32; off > 0; off >>= 1) {
            p1 += __shfl_down(p1, off);
            p2 += __shfl_down(p2, off);
        }
        if (lane == 0) {
            float z1 = p1 + bias2;   // target 1
            float z2 = p2 + bias2;   // target 0
            bce_acc += fmaxf(z1, 0.f) - z1 + log1pf(expf(-fabsf(z1)));
            bce_acc += fmaxf(z2, 0.f)      + log1pf(expf(-fabsf(z2)));
            corr_acc += (z1 > 0.f) ? 1.f : 0.f;
            corr_acc += (z2 > 0.f) ? 0.f : 1.f;
        }
    }
    if (lane == 0) { red[0][wv] = bce_acc; red[1][wv] = corr_acc; }
    __syncthreads();
    if (threadIdx.x == 0) {
        const float scale = 1.f / (2.f * BATCH);
        atomicAdd(&out[0], (red[0][0] + red[0][1] + red[0][2] + red[0][3]) * scale);
        atomicAdd(&out[1], (red[1][0] + red[1][1] + red[1][2] + red[1][3]) * scale);
    }
}

// ---------------------------------------------------------------------------
extern "C" void kernel_launch(void* const* d_in, const int* in_sizes, int n_in,
                              void* d_out, int out_size, void* d_ws, size_t ws_size,
                              hipStream_t stream) {
    const int*   bill  = (const int*)d_in[0];
    const int*   u1    = (const int*)d_in[1];
    const int*   u2    = (const int*)d_in[2];
    const int*   ei    = (const int*)d_in[3];
    const int*   et    = (const int*)d_in[4];
    const float* uf    = (const float*)d_in[5];
    const float* W1    = (const float*)d_in[6];
    const float* root1 = (const float*)d_in[7];
    const float* b1    = (const float*)d_in[8];
    const float* W2    = (const float*)d_in[9];
    const float* root2 = (const float*)d_in[10];
    const float* b2    = (const float*)d_in[11];
    const float* m1w   = (const float*)d_in[12];
    const float* m1b   = (const float*)d_in[13];
    const float* m2w   = (const float*)d_in[14];
    const float* m2b   = (const float*)d_in[15];
    float* out = (float*)d_out;

    // ws layout (peak 105,452,816 B < proven 106,400,000 B):
    //   0           h_all     76,800,000   [100000][384] bf16
    //  76,800,000   sorted    12,800,000   u32 keys, (dst,rel)-segment order
    //  89,600,000   bucketed  12,800,000   u32 keys, bucket order (dead after
    //                                      seg_sort; xbuf aliases here)
    // 102,400,000   hist         800,768   [256][782] int
    // 103,200,768   btot           3,128
    // 103,203,896   boffs          3,132   (783 ints)
    // 103,207,040   offs       2,000,004   (NSEG+1 ints)
    // 105,207,056   BT1          196,608
    // 105,403,664   BT2           49,152
    char* ws = (char*)d_ws;
    u16* h_all    = (u16*)(ws);
    u32* sorted   = (u32*)(ws + 76800000);
    u32* bucketed = (u32*)(ws + 89600000);
    u16* xbuf     = (u16*)(ws + 89600000);   // alias: valid after seg_sort
    int* hist     = (int*)(ws + 102400000);
    int* btot     = (int*)(ws + 103200768);
    int* boffs    = (int*)(ws + 103203896);
    int* offs     = (int*)(ws + 103207040);
    u16* BT1      = (u16*)(ws + 105207056);
    u16* BT2      = (u16*)(ws + 105403664);
    if (ws_size < 105452816) return;  // fail visibly

    const int* src = ei;
    const int* dst = ei + N_EDGES;

    hipMemsetAsync(d_out, 0, 2 * sizeof(float), stream);

    // ---- two-level bucket sort into (dst,rel) segment order
    bucket_hist<<<NWG1, 256, 0, stream>>>(dst, hist);
    col_scan<<<NB, 64, 0, stream>>>(hist, btot);
    btot_scan<<<1, 64, 0, stream>>>(btot, boffs, offs);
    bucket_scatter<<<NWG1, 256, 0, stream>>>(src, dst, et, hist, boffs, bucketed);
    seg_sort<<<NB, 256, 0, stream>>>(bucketed, boffs, offs, sorted);

    // ---- pack weights to BT (bf16, [384][K])
    build_bt<<<(384 * EMB + 255) / 256, 256, 0, stream>>>(W1, root1, EMB, BT1);
    build_bt<<<(384 * HID + 255) / 256, 256, 0, stream>>>(W2, root2, HID, BT2);

    // ---- Layer 1
    mfma_gemm<EMB, true><<<dim3(782, 3), 256, 0, stream>>>(uf, BT1, h_all);
    agg_flat<true><<<25000, 256, 0, stream>>>(h_all, sorted, offs, b1, xbuf);

    // ---- Layer 2
    mfma_gemm<HID, false><<<dim3(782, 3), 256, 0, stream>>>(xbuf, BT2, h_all);
    agg_flat<false><<<25000, 256, 0, stream>>>(h_all, sorted, offs, b2, xbuf);

    // ---- Merge MLP + BCE + accuracy
    loss_kernel<<<128, 256, 0, stream>>>(xbuf, bill, u1, u2, m1w, m1b, m2w, m2b, out);
}

// Round 7
// 825.853 us; speedup vs baseline: 3.6728x; 1.0931x over previous
//
#include <hip/hip_runtime.h>
#include <hip/hip_bf16.h>

#define N_NODES 100000
#define EMB 256
#define HID 64
#define N_REL 5
#define N_EDGES 3200000
#define BATCH 16384
#define NB 782                 // buckets of 128 dst nodes
#define NWG1 256               // scatter/hist WGs
#define CH 12500               // edges per WG chunk (256*12500 = 3.2M exact)
#define LSEG 640               // 128 nodes * 5 rels
#define NSEG (N_NODES * N_REL) // 500000

typedef unsigned short u16;
typedef unsigned int u32;
typedef __attribute__((ext_vector_type(4))) float f32x4;
typedef __attribute__((ext_vector_type(8))) short short8;

__device__ __forceinline__ float bf2f(u16 u) {
    union { float f; u32 i; } v;
    v.i = ((u32)u) << 16;
    return v.f;
}
__device__ __forceinline__ u16 f2bf(float f) {
    union { float f; u32 i; } v;
    v.f = f;
    u32 r = v.i + 0x7fff + ((v.i >> 16) & 1);   // RNE
    return (u16)(r >> 16);
}

__device__ __forceinline__ void gload_lds16(const void* g, void* l) {
    __builtin_amdgcn_global_load_lds(
        (const __attribute__((address_space(1))) unsigned int*)g,
        (__attribute__((address_space(3))) unsigned int*)l, 16, 0, 0);
}

// ---------------------------------------------------------------------------
// K1: per-WG bucket histogram (deterministic chunks, no global atomics)
// ---------------------------------------------------------------------------
__global__ __launch_bounds__(256) void bucket_hist(const int* __restrict__ dst,
                                                   int* __restrict__ hist) {
    __shared__ int hl[NB];
    const int tid = threadIdx.x;
    for (int i = tid; i < NB; i += 256) hl[i] = 0;
    __syncthreads();
    const int w = blockIdx.x;
    const int s = w * CH, e = s + CH;
    for (int i = s + tid; i < e; i += 256)
        atomicAdd(&hl[dst[i] >> 7], 1);
    __syncthreads();
    for (int i = tid; i < NB; i += 256) hist[w * NB + i] = hl[i];
}

// ---------------------------------------------------------------------------
// K2a: per-bucket column scan over WGs (in-place hist -> base_local), btot out
// ---------------------------------------------------------------------------
__global__ void col_scan(int* __restrict__ hist, int* __restrict__ btot) {
    const int b = blockIdx.x;
    const int lane = threadIdx.x;
    int carry = 0;
    for (int c = 0; c < NWG1; c += 64) {
        int v = hist[(c + lane) * NB + b];
        int incl = v;
#pragma unroll
        for (int off = 1; off < 64; off <<= 1) {
            int t = __shfl_up(incl, off);
            if (lane >= off) incl += t;
        }
        hist[(c + lane) * NB + b] = carry + (incl - v);
        carry += __shfl(incl, 63);
    }
    if (lane == 0) btot[b] = carry;
}

// ---------------------------------------------------------------------------
// K2b: scan bucket totals -> bucket offsets (+ sentinels)
// ---------------------------------------------------------------------------
__global__ void btot_scan(const int* __restrict__ btot, int* __restrict__ boffs,
                          int* __restrict__ offs) {
    const int lane = threadIdx.x;
    int carry = 0;
    for (int c = 0; c < NB; c += 64) {
        int v = (c + lane < NB) ? btot[c + lane] : 0;
        int incl = v;
#pragma unroll
        for (int off = 1; off < 64; off <<= 1) {
            int t = __shfl_up(incl, off);
            if (lane >= off) incl += t;
        }
        if (c + lane < NB) boffs[c + lane] = carry + (incl - v);
        carry += __shfl(incl, 63);
    }
    if (lane == 0) {
        boffs[NB] = N_EDGES;
        offs[NSEG] = N_EDGES;   // global sentinel for offs-diff degree
    }
}

// ---------------------------------------------------------------------------
// K3: scatter packed keys into bucket-ordered array (LDS cursors -> bursts)
// key = src | ((ldst*5 + et) << 17)
// ---------------------------------------------------------------------------
__global__ __launch_bounds__(256) void bucket_scatter(
        const int* __restrict__ src, const int* __restrict__ dst,
        const int* __restrict__ et, const int* __restrict__ base,
        const int* __restrict__ boffs, u32* __restrict__ bucketed) {
    __shared__ int cur[NB];
    const int tid = threadIdx.x;
    const int w = blockIdx.x;
    for (int i = tid; i < NB; i += 256) cur[i] = boffs[i] + base[w * NB + i];
    __syncthreads();
    const int s = w * CH, e = s + CH;
    for (int i = s + tid; i < e; i += 256) {
        int d = dst[i];
        int b = d >> 7;
        u32 key = (u32)src[i] | ((u32)((d & 127) * 5 + et[i]) << 17);
        int pos = atomicAdd(&cur[b], 1);
        bucketed[pos] = key;
    }
}

// ---------------------------------------------------------------------------
// K4: within-bucket segment sort. One WG per bucket: LDS histogram of 640
// local segs -> wave scan -> global offs + LDS-cursor scatter.
// Output = precomputed gather ELEMENT offset: src*384 + rel*64 (fits u32).
// ---------------------------------------------------------------------------
__global__ __launch_bounds__(256) void seg_sort(
        const u32* __restrict__ keys, const int* __restrict__ boffs,
        int* __restrict__ offs, u32* __restrict__ soff) {
    __shared__ int cntl[LSEG];
    __shared__ int cur[LSEG];
    const int tid = threadIdx.x;
    const int b = blockIdx.x;
    const int s = boffs[b], e = boffs[b + 1];

    for (int i = tid; i < LSEG; i += 256) cntl[i] = 0;
    __syncthreads();
    for (int i = s + tid; i < e; i += 256)
        atomicAdd(&cntl[keys[i] >> 17], 1);
    __syncthreads();

    if (tid < 64) {   // wave 0: exclusive scan of 640 counts
        int carry = 0;
        for (int c = 0; c < LSEG; c += 64) {
            int v = cntl[c + tid];
            int incl = v;
#pragma unroll
            for (int off = 1; off < 64; off <<= 1) {
                int t = __shfl_up(incl, off);
                if (tid >= off) incl += t;
            }
            cur[c + tid] = carry + (incl - v);
            carry += __shfl(incl, 63);
        }
    }
    __syncthreads();

    const int segbase = b * LSEG;   // == (b*128)*5
    for (int i = tid; i < LSEG; i += 256)
        if (segbase + i < NSEG) offs[segbase + i] = s + cur[i];
    __syncthreads();

    for (int i = s + tid; i < e; i += 256) {
        u32 key = keys[i];
        u32 lseg = key >> 17;
        int pos = s + atomicAdd(&cur[lseg], 1);
        u32 q = (lseg * 52429u) >> 18;          // lseg / 5
        u32 rel = lseg - q * 5u;
        soff[pos] = (key & 0x1FFFF) * 384u + rel * 64u;
    }
}

// ---------------------------------------------------------------------------
// Pack weights: BT[j][k] = (j<320 ? W[j>>6][k][j&63] : root[k][j&63]) as bf16
// ---------------------------------------------------------------------------
__global__ void build_bt(const float* __restrict__ W, const float* __restrict__ root,
                         int K, u16* __restrict__ BT) {
    int idx = blockIdx.x * blockDim.x + threadIdx.x;
    if (idx >= 384 * K) return;
    int j = idx / K, k = idx - j * K;
    float v = (j < 320) ? W[((j >> 6) * K + k) * 64 + (j & 63)]
                        : root[k * 64 + (j & 63)];
    BT[idx] = f2bf(v);
}

// ---------------------------------------------------------------------------
// MFMA GEMM: C[100000][384](bf16) = A[100000][K] x BT[384][K]^T
// (unchanged — verified correct)
// ---------------------------------------------------------------------------
template <int K, bool A_F32>
__global__ __launch_bounds__(256) void mfma_gemm(
        const void* __restrict__ Av, const u16* __restrict__ BT,
        u16* __restrict__ C) {
    __shared__ __align__(16) u16 Al[128 * 64];
    __shared__ __align__(16) u16 Bl[128 * 64];
    const int tid  = threadIdx.x;
    const int lane = tid & 63;
    const int wave = tid >> 6;
    const int m0 = blockIdx.x * 128;
    const int n0 = blockIdx.y * 128;
    const int wr = (wave >> 1) * 64;
    const int wc = (wave & 1) * 64;
    const int l15 = lane & 15;
    const int lg  = lane >> 4;

    f32x4 acc[4][4];
#pragma unroll
    for (int i = 0; i < 4; ++i)
#pragma unroll
        for (int j = 0; j < 4; ++j) {
            f32x4 z = {0.f, 0.f, 0.f, 0.f};
            acc[i][j] = z;
        }

    for (int k0 = 0; k0 < K; k0 += 64) {
#pragma unroll
        for (int i = 0; i < 4; ++i) {
            int c = wave * 4 + i;
            int row = c * 8 + (lane >> 3);
            int kk  = (lane & 7) * 8;
            gload_lds16(BT + (size_t)(n0 + row) * K + k0 + kk, &Bl[c * 512]);
        }
        if (A_F32) {
            const float* Af = (const float*)Av;
#pragma unroll
            for (int p = 0; p < 8; ++p) {
                int f = p * 1024 + tid * 4;
                int row = f >> 6;
                int col = f & 63;
                int gr = m0 + row;
                if (gr > N_NODES - 1) gr = N_NODES - 1;
                float4 v = *(const float4*)(Af + (size_t)gr * K + k0 + col);
                ushort4 o;
                o.x = f2bf(v.x); o.y = f2bf(v.y); o.z = f2bf(v.z); o.w = f2bf(v.w);
                *(ushort4*)&Al[row * 64 + col] = o;
            }
        } else {
            const u16* Ab = (const u16*)Av;
#pragma unroll
            for (int i = 0; i < 4; ++i) {
                int c = wave * 4 + i;
                int row = c * 8 + (lane >> 3);
                int kk  = (lane & 7) * 8;
                gload_lds16(Ab + (size_t)(m0 + row) * K + k0 + kk, &Al[c * 512]);
            }
        }
        __syncthreads();

#pragma unroll
        for (int kk = 0; kk < 64; kk += 32) {
            short8 af[4], bf[4];
#pragma unroll
            for (int f = 0; f < 4; ++f) {
                af[f] = *(const short8*)&Al[(wr + f * 16 + l15) * 64 + kk + lg * 8];
                bf[f] = *(const short8*)&Bl[(wc + f * 16 + l15) * 64 + kk + lg * 8];
            }
#pragma unroll
            for (int fm = 0; fm < 4; ++fm)
#pragma unroll
                for (int fn = 0; fn < 4; ++fn)
                    acc[fm][fn] = __builtin_amdgcn_mfma_f32_16x16x32_bf16(
                        af[fm], bf[fn], acc[fm][fn], 0, 0, 0);
        }
        __syncthreads();
    }

#pragma unroll
    for (int fm = 0; fm < 4; ++fm) {
        int rbase = m0 + wr + fm * 16 + lg * 4;
#pragma unroll
        for (int i = 0; i < 4; ++i) {
            int r = rbase + i;
            if (r < N_NODES) {
#pragma unroll
                for (int fn = 0; fn < 4; ++fn)
                    C[(size_t)r * 384 + n0 + wc + fn * 16 + l15] = f2bf(acc[fm][fn][i]);
            }
        }
    }
}

// ---------------------------------------------------------------------------
// Aggregate (segmented, low-VALU): one wave per dst node, lane = feature.
// Per-rel segment loops; gather address = precomputed element offset + lane;
// mean weight applied once per segment; 8 guarded loads per unrolled block.
// ---------------------------------------------------------------------------
template <bool RELU>
__global__ __launch_bounds__(256) void agg_seg(
        const u16* __restrict__ h, const u32* __restrict__ soff,
        const int* __restrict__ offs, const float* __restrict__ bias,
        u16* __restrict__ out) {
    const int lane = threadIdx.x & 63;
    const int d = (blockIdx.x * blockDim.x + threadIdx.x) >> 6;
    if (d >= N_NODES) return;

    const u16* hl = h + lane;
    float acc = bf2f(h[(size_t)d * 384 + 320 + lane]) + bias[lane];
    int ob = offs[d * 5];
#pragma unroll
    for (int r = 0; r < N_REL; ++r) {
        int oe = offs[d * 5 + r + 1];
        int n = oe - ob;
        if (n > 0) {
            float s0 = 0.f, s1 = 0.f;
            for (int k = ob; k < oe; k += 8) {
#pragma unroll
                for (int j = 0; j < 8; j += 2) {
                    if (k + j < oe)     s0 += bf2f(hl[soff[k + j]]);
                    if (k + j + 1 < oe) s1 += bf2f(hl[soff[k + j + 1]]);
                }
            }
            acc += (s0 + s1) * (1.0f / (float)n);
        }
        ob = oe;
    }
    if (RELU) acc = fmaxf(acc, 0.f);
    out[(size_t)d * 64 + lane] = f2bf(acc);
}

// ---------------------------------------------------------------------------
// Merge MLP + BCE/accuracy (nodes in bf16)
// ---------------------------------------------------------------------------
__global__ __launch_bounds__(256) void loss_kernel(
        const u16* __restrict__ nodes, const int* __restrict__ bill,
        const int* __restrict__ u1, const int* __restrict__ u2,
        const float* __restrict__ w1, const float* __restrict__ b1,
        const float* __restrict__ w2, const float* __restrict__ b2,
        float* __restrict__ out) {
    __shared__ float Wl[128 * 64];
    __shared__ float red[2][4];
    for (int j = threadIdx.x; j < 128 * 16; j += 256)
        ((float4*)Wl)[j] = ((const float4*)w1)[j];
    __syncthreads();

    const int lane = threadIdx.x & 63;
    const int wv   = threadIdx.x >> 6;
    const int gw   = blockIdx.x * 4 + wv;
    const int nw   = gridDim.x * 4;

    const float bias1 = b1[lane];
    const float w2l   = w2[lane];
    const float bias2 = b2[0];

    float bce_acc = 0.f, corr_acc = 0.f;
    for (int s = gw; s < BATCH; s += nw) {
        const u16* xb  = nodes + (size_t)bill[s] * 64;
        const u16* xu1 = nodes + (size_t)u1[s] * 64;
        const u16* xu2 = nodes + (size_t)u2[s] * 64;
        float hb = bias1, h1 = 0.f, h2 = 0.f;
#pragma unroll 8
        for (int i = 0; i < 64; ++i) {
            float wb = Wl[i * 64 + lane];
            float wu = Wl[(64 + i) * 64 + lane];
            hb += bf2f(xb[i]) * wb;
            h1 += bf2f(xu1[i]) * wu;
            h2 += bf2f(xu2[i]) * wu;
        }
        float p1 = fmaxf(hb + h1, 0.f) * w2l;
        float p2 = fmaxf(hb + h2, 0.f) * w2l;
#pragma unroll
        for (int off = 32; off > 0; off >>= 1) {
            p1 += __shfl_down(p1, off);
            p2 += __shfl_down(p2, off);
        }
        if (lane == 0) {
            float z1 = p1 + bias2;   // target 1
            float z2 = p2 + bias2;   // target 0
            bce_acc += fmaxf(z1, 0.f) - z1 + log1pf(expf(-fabsf(z1)));
            bce_acc += fmaxf(z2, 0.f)      + log1pf(expf(-fabsf(z2)));
            corr_acc += (z1 > 0.f) ? 1.f : 0.f;
            corr_acc += (z2 > 0.f) ? 0.f : 1.f;
        }
    }
    if (lane == 0) { red[0][wv] = bce_acc; red[1][wv] = corr_acc; }
    __syncthreads();
    if (threadIdx.x == 0) {
        const float scale = 1.f / (2.f * BATCH);
        atomicAdd(&out[0], (red[0][0] + red[0][1] + red[0][2] + red[0][3]) * scale);
        atomicAdd(&out[1], (red[1][0] + red[1][1] + red[1][2] + red[1][3]) * scale);
    }
}

// ---------------------------------------------------------------------------
extern "C" void kernel_launch(void* const* d_in, const int* in_sizes, int n_in,
                              void* d_out, int out_size, void* d_ws, size_t ws_size,
                              hipStream_t stream) {
    const int*   bill  = (const int*)d_in[0];
    const int*   u1    = (const int*)d_in[1];
    const int*   u2    = (const int*)d_in[2];
    const int*   ei    = (const int*)d_in[3];
    const int*   et    = (const int*)d_in[4];
    const float* uf    = (const float*)d_in[5];
    const float* W1    = (const float*)d_in[6];
    const float* root1 = (const float*)d_in[7];
    const float* b1    = (const float*)d_in[8];
    const float* W2    = (const float*)d_in[9];
    const float* root2 = (const float*)d_in[10];
    const float* b2    = (const float*)d_in[11];
    const float* m1w   = (const float*)d_in[12];
    const float* m1b   = (const float*)d_in[13];
    const float* m2w   = (const float*)d_in[14];
    const float* m2b   = (const float*)d_in[15];
    float* out = (float*)d_out;

    // ws layout (peak 105,452,816 B < proven 106,400,000 B):
    //   0           h_all     76,800,000   [100000][384] bf16
    //  76,800,000   sorted    12,800,000   u32 gather element-offsets
    //  89,600,000   bucketed  12,800,000   u32 keys, bucket order (dead after
    //                                      seg_sort; xbuf aliases here)
    // 102,400,000   hist         800,768   [256][782] int
    // 103,200,768   btot           3,128
    // 103,203,896   boffs          3,132   (783 ints)
    // 103,207,040   offs       2,000,004   (NSEG+1 ints)
    // 105,207,056   BT1          196,608
    // 105,403,664   BT2           49,152
    char* ws = (char*)d_ws;
    u16* h_all    = (u16*)(ws);
    u32* sorted   = (u32*)(ws + 76800000);
    u32* bucketed = (u32*)(ws + 89600000);
    u16* xbuf     = (u16*)(ws + 89600000);   // alias: valid after seg_sort
    int* hist     = (int*)(ws + 102400000);
    int* btot     = (int*)(ws + 103200768);
    int* boffs    = (int*)(ws + 103203896);
    int* offs     = (int*)(ws + 103207040);
    u16* BT1      = (u16*)(ws + 105207056);
    u16* BT2      = (u16*)(ws + 105403664);
    if (ws_size < 105452816) return;  // fail visibly

    const int* src = ei;
    const int* dst = ei + N_EDGES;

    hipMemsetAsync(d_out, 0, 2 * sizeof(float), stream);

    // ---- two-level bucket sort into (dst,rel) segment order
    bucket_hist<<<NWG1, 256, 0, stream>>>(dst, hist);
    col_scan<<<NB, 64, 0, stream>>>(hist, btot);
    btot_scan<<<1, 64, 0, stream>>>(btot, boffs, offs);
    bucket_scatter<<<NWG1, 256, 0, stream>>>(src, dst, et, hist, boffs, bucketed);
    seg_sort<<<NB, 256, 0, stream>>>(bucketed, boffs, offs, sorted);

    // ---- pack weights to BT (bf16, [384][K])
    build_bt<<<(384 * EMB + 255) / 256, 256, 0, stream>>>(W1, root1, EMB, BT1);
    build_bt<<<(384 * HID + 255) / 256, 256, 0, stream>>>(W2, root2, HID, BT2);

    // ---- Layer 1
    mfma_gemm<EMB, true><<<dim3(782, 3), 256, 0, stream>>>(uf, BT1, h_all);
    agg_seg<true><<<25000, 256, 0, stream>>>(h_all, sorted, offs, b1, xbuf);

    // ---- Layer 2
    mfma_gemm<HID, false><<<dim3(782, 3), 256, 0, stream>>>(xbuf, BT2, h_all);
    agg_seg<false><<<25000, 256, 0, stream>>>(h_all, sorted, offs, b2, xbuf);

    // ---- Merge MLP + BCE + accuracy
    loss_kernel<<<128, 256, 0, stream>>>(xbuf, bill, u1, u2, m1w, m1b, m2w, m2b, out);
}

// Round 8
// 414.972 us; speedup vs baseline: 7.3093x; 1.9901x over previous
//
#include <hip/hip_runtime.h>
#include <hip/hip_bf16.h>

#define N_NODES 100000
#define EMB 256
#define HID 64
#define N_REL 5
#define N_EDGES 3200000
#define BATCH 16384
#define NB 782                 // buckets of 128 dst nodes
#define NWG1 256               // scatter/hist WGs
#define CH 12500               // edges per WG chunk (256*12500 = 3.2M exact)
#define LSEG 640               // 128 nodes * 5 rels
#define NSEG (N_NODES * N_REL) // 500000

typedef unsigned short u16;
typedef unsigned int u32;
typedef __attribute__((ext_vector_type(4))) float f32x4;
typedef __attribute__((ext_vector_type(8))) short short8;

__device__ __forceinline__ float bf2f(u16 u) {
    union { float f; u32 i; } v;
    v.i = ((u32)u) << 16;
    return v.f;
}
__device__ __forceinline__ u16 f2bf(float f) {
    union { float f; u32 i; } v;
    v.f = f;
    u32 r = v.i + 0x7fff + ((v.i >> 16) & 1);   // RNE
    return (u16)(r >> 16);
}

__device__ __forceinline__ void gload_lds16(const void* g, void* l) {
    __builtin_amdgcn_global_load_lds(
        (const __attribute__((address_space(1))) unsigned int*)g,
        (__attribute__((address_space(3))) unsigned int*)l, 16, 0, 0);
}

// ---------------------------------------------------------------------------
// K1: per-WG bucket histogram (deterministic chunks, no global atomics)
// ---------------------------------------------------------------------------
__global__ __launch_bounds__(256) void bucket_hist(const int* __restrict__ dst,
                                                   int* __restrict__ hist) {
    __shared__ int hl[NB];
    const int tid = threadIdx.x;
    for (int i = tid; i < NB; i += 256) hl[i] = 0;
    __syncthreads();
    const int w = blockIdx.x;
    const int s = w * CH, e = s + CH;
    for (int i = s + tid; i < e; i += 256)
        atomicAdd(&hl[dst[i] >> 7], 1);
    __syncthreads();
    for (int i = tid; i < NB; i += 256) hist[w * NB + i] = hl[i];
}

// ---------------------------------------------------------------------------
// K2a: per-bucket column scan over WGs (in-place hist -> base_local), btot out
// ---------------------------------------------------------------------------
__global__ void col_scan(int* __restrict__ hist, int* __restrict__ btot) {
    const int b = blockIdx.x;
    const int lane = threadIdx.x;
    int carry = 0;
    for (int c = 0; c < NWG1; c += 64) {
        int v = hist[(c + lane) * NB + b];
        int incl = v;
#pragma unroll
        for (int off = 1; off < 64; off <<= 1) {
            int t = __shfl_up(incl, off);
            if (lane >= off) incl += t;
        }
        hist[(c + lane) * NB + b] = carry + (incl - v);
        carry += __shfl(incl, 63);
    }
    if (lane == 0) btot[b] = carry;
}

// ---------------------------------------------------------------------------
// K2b: scan bucket totals -> bucket offsets (+ sentinels)
// ---------------------------------------------------------------------------
__global__ void btot_scan(const int* __restrict__ btot, int* __restrict__ boffs,
                          int* __restrict__ offs) {
    const int lane = threadIdx.x;
    int carry = 0;
    for (int c = 0; c < NB; c += 64) {
        int v = (c + lane < NB) ? btot[c + lane] : 0;
        int incl = v;
#pragma unroll
        for (int off = 1; off < 64; off <<= 1) {
            int t = __shfl_up(incl, off);
            if (lane >= off) incl += t;
        }
        if (c + lane < NB) boffs[c + lane] = carry + (incl - v);
        carry += __shfl(incl, 63);
    }
    if (lane == 0) {
        boffs[NB] = N_EDGES;
        offs[NSEG] = N_EDGES;   // global sentinel for offs-diff degree
    }
}

// ---------------------------------------------------------------------------
// K3: scatter packed keys into bucket-ordered array (LDS cursors -> bursts)
// key = src | ((ldst*5 + et) << 17)
// ---------------------------------------------------------------------------
__global__ __launch_bounds__(256) void bucket_scatter(
        const int* __restrict__ src, const int* __restrict__ dst,
        const int* __restrict__ et, const int* __restrict__ base,
        const int* __restrict__ boffs, u32* __restrict__ bucketed) {
    __shared__ int cur[NB];
    const int tid = threadIdx.x;
    const int w = blockIdx.x;
    for (int i = tid; i < NB; i += 256) cur[i] = boffs[i] + base[w * NB + i];
    __syncthreads();
    const int s = w * CH, e = s + CH;
    for (int i = s + tid; i < e; i += 256) {
        int d = dst[i];
        int b = d >> 7;
        u32 key = (u32)src[i] | ((u32)((d & 127) * 5 + et[i]) << 17);
        int pos = atomicAdd(&cur[b], 1);
        bucketed[pos] = key;
    }
}

// ---------------------------------------------------------------------------
// K4: within-bucket segment sort. One WG per bucket: LDS histogram of 640
// local segs -> wave scan -> global offs + LDS-cursor scatter.
// Output = precomputed gather ELEMENT offset: src*384 + rel*64 (fits u32).
// ---------------------------------------------------------------------------
__global__ __launch_bounds__(256) void seg_sort(
        const u32* __restrict__ keys, const int* __restrict__ boffs,
        int* __restrict__ offs, u32* __restrict__ soff) {
    __shared__ int cntl[LSEG];
    __shared__ int cur[LSEG];
    const int tid = threadIdx.x;
    const int b = blockIdx.x;
    const int s = boffs[b], e = boffs[b + 1];

    for (int i = tid; i < LSEG; i += 256) cntl[i] = 0;
    __syncthreads();
    for (int i = s + tid; i < e; i += 256)
        atomicAdd(&cntl[keys[i] >> 17], 1);
    __syncthreads();

    if (tid < 64) {   // wave 0: exclusive scan of 640 counts
        int carry = 0;
        for (int c = 0; c < LSEG; c += 64) {
            int v = cntl[c + tid];
            int incl = v;
#pragma unroll
            for (int off = 1; off < 64; off <<= 1) {
                int t = __shfl_up(incl, off);
                if (tid >= off) incl += t;
            }
            cur[c + tid] = carry + (incl - v);
            carry += __shfl(incl, 63);
        }
    }
    __syncthreads();

    const int segbase = b * LSEG;   // == (b*128)*5
    for (int i = tid; i < LSEG; i += 256)
        if (segbase + i < NSEG) offs[segbase + i] = s + cur[i];
    __syncthreads();

    for (int i = s + tid; i < e; i += 256) {
        u32 key = keys[i];
        u32 lseg = key >> 17;
        int pos = s + atomicAdd(&cur[lseg], 1);
        u32 q = (lseg * 52429u) >> 18;          // lseg / 5
        u32 rel = lseg - q * 5u;
        soff[pos] = (key & 0x1FFFF) * 384u + rel * 64u;
    }
}

// ---------------------------------------------------------------------------
// Pack weights: BT[j][k] = (j<320 ? W[j>>6][k][j&63] : root[k][j&63]) as bf16
// ---------------------------------------------------------------------------
__global__ void build_bt(const float* __restrict__ W, const float* __restrict__ root,
                         int K, u16* __restrict__ BT) {
    int idx = blockIdx.x * blockDim.x + threadIdx.x;
    if (idx >= 384 * K) return;
    int j = idx / K, k = idx - j * K;
    float v = (j < 320) ? W[((j >> 6) * K + k) * 64 + (j & 63)]
                        : root[k * 64 + (j & 63)];
    BT[idx] = f2bf(v);
}

// ---------------------------------------------------------------------------
// MFMA GEMM: C[100000][384](bf16) = A[100000][K] x BT[384][K]^T
// (unchanged — verified correct)
// ---------------------------------------------------------------------------
template <int K, bool A_F32>
__global__ __launch_bounds__(256) void mfma_gemm(
        const void* __restrict__ Av, const u16* __restrict__ BT,
        u16* __restrict__ C) {
    __shared__ __align__(16) u16 Al[128 * 64];
    __shared__ __align__(16) u16 Bl[128 * 64];
    const int tid  = threadIdx.x;
    const int lane = tid & 63;
    const int wave = tid >> 6;
    const int m0 = blockIdx.x * 128;
    const int n0 = blockIdx.y * 128;
    const int wr = (wave >> 1) * 64;
    const int wc = (wave & 1) * 64;
    const int l15 = lane & 15;
    const int lg  = lane >> 4;

    f32x4 acc[4][4];
#pragma unroll
    for (int i = 0; i < 4; ++i)
#pragma unroll
        for (int j = 0; j < 4; ++j) {
            f32x4 z = {0.f, 0.f, 0.f, 0.f};
            acc[i][j] = z;
        }

    for (int k0 = 0; k0 < K; k0 += 64) {
#pragma unroll
        for (int i = 0; i < 4; ++i) {
            int c = wave * 4 + i;
            int row = c * 8 + (lane >> 3);
            int kk  = (lane & 7) * 8;
            gload_lds16(BT + (size_t)(n0 + row) * K + k0 + kk, &Bl[c * 512]);
        }
        if (A_F32) {
            const float* Af = (const float*)Av;
#pragma unroll
            for (int p = 0; p < 8; ++p) {
                int f = p * 1024 + tid * 4;
                int row = f >> 6;
                int col = f & 63;
                int gr = m0 + row;
                if (gr > N_NODES - 1) gr = N_NODES - 1;
                float4 v = *(const float4*)(Af + (size_t)gr * K + k0 + col);
                ushort4 o;
                o.x = f2bf(v.x); o.y = f2bf(v.y); o.z = f2bf(v.z); o.w = f2bf(v.w);
                *(ushort4*)&Al[row * 64 + col] = o;
            }
        } else {
            const u16* Ab = (const u16*)Av;
#pragma unroll
            for (int i = 0; i < 4; ++i) {
                int c = wave * 4 + i;
                int row = c * 8 + (lane >> 3);
                int kk  = (lane & 7) * 8;
                gload_lds16(Ab + (size_t)(m0 + row) * K + k0 + kk, &Al[c * 512]);
            }
        }
        __syncthreads();

#pragma unroll
        for (int kk = 0; kk < 64; kk += 32) {
            short8 af[4], bf[4];
#pragma unroll
            for (int f = 0; f < 4; ++f) {
                af[f] = *(const short8*)&Al[(wr + f * 16 + l15) * 64 + kk + lg * 8];
                bf[f] = *(const short8*)&Bl[(wc + f * 16 + l15) * 64 + kk + lg * 8];
            }
#pragma unroll
            for (int fm = 0; fm < 4; ++fm)
#pragma unroll
                for (int fn = 0; fn < 4; ++fn)
                    acc[fm][fn] = __builtin_amdgcn_mfma_f32_16x16x32_bf16(
                        af[fm], bf[fn], acc[fm][fn], 0, 0, 0);
        }
        __syncthreads();
    }

#pragma unroll
    for (int fm = 0; fm < 4; ++fm) {
        int rbase = m0 + wr + fm * 16 + lg * 4;
#pragma unroll
        for (int i = 0; i < 4; ++i) {
            int r = rbase + i;
            if (r < N_NODES) {
#pragma unroll
                for (int fn = 0; fn < 4; ++fn)
                    C[(size_t)r * 384 + n0 + wc + fn * 16 + l15] = f2bf(acc[fm][fn][i]);
            }
        }
    }
}

// ---------------------------------------------------------------------------
// Aggregate (readlane): one wave per dst node, lane = feature.
// Per 64-edge chunk: ONE coalesced load of 64 offsets + per-lane weight;
// inner loop broadcasts offset/weight via v_readlane (SGPR) so the gather is
// SGPR-base + lane*2 and loads issue back-to-back (no scalar-load chain).
// Tail edges get weight 0 with clamped offsets -> no inner-loop guards.
// ---------------------------------------------------------------------------
template <bool RELU>
__global__ __launch_bounds__(256) void agg_rl(
        const u16* __restrict__ h, const u32* __restrict__ soff,
        const int* __restrict__ offs, const float* __restrict__ bias,
        u16* __restrict__ out) {
    const int lane = threadIdx.x & 63;
    const int d = (blockIdx.x * blockDim.x + threadIdx.x) >> 6;
    if (d >= N_NODES) return;

    const int o0 = offs[d * 5 + 0], o1 = offs[d * 5 + 1], o2 = offs[d * 5 + 2];
    const int o3 = offs[d * 5 + 3], o4 = offs[d * 5 + 4], o5 = offs[d * 5 + 5];
    const float i0 = 1.f / (float)max(o1 - o0, 1);
    const float i1 = 1.f / (float)max(o2 - o1, 1);
    const float i2 = 1.f / (float)max(o3 - o2, 1);
    const float i3 = 1.f / (float)max(o4 - o3, 1);
    const float i4 = 1.f / (float)max(o5 - o4, 1);

    const u16* hl = h + lane;
    float acc0 = bf2f(h[(size_t)d * 384 + 320 + lane]) + bias[lane];
    float acc1 = 0.f;

    for (int base = o0; base < o5; base += 64) {
        const int idx = base + lane;
        const u32 voff = soff[min(idx, o5 - 1)];          // coalesced, clamped
        float wv = idx < o1 ? i0 : idx < o2 ? i1 : idx < o3 ? i2
                 : idx < o4 ? i3 : i4;
        if (idx >= o5) wv = 0.f;                          // tail contributes 0
        const int m = min(64, o5 - base);
        for (int j = 0; j < m; j += 8) {
#pragma unroll
            for (int jj = 0; jj < 8; jj += 2) {
                int  offa = __builtin_amdgcn_readlane((int)voff, j + jj);
                int  wa_i = __builtin_amdgcn_readlane((int)__float_as_uint(wv), j + jj);
                int  offb = __builtin_amdgcn_readlane((int)voff, j + jj + 1);
                int  wb_i = __builtin_amdgcn_readlane((int)__float_as_uint(wv), j + jj + 1);
                acc0 += bf2f(hl[(u32)offa]) * __uint_as_float((u32)wa_i);
                acc1 += bf2f(hl[(u32)offb]) * __uint_as_float((u32)wb_i);
            }
        }
    }
    float acc = acc0 + acc1;
    if (RELU) acc = fmaxf(acc, 0.f);
    out[(size_t)d * 64 + lane] = f2bf(acc);
}

// ---------------------------------------------------------------------------
// Merge MLP + BCE/accuracy (nodes in bf16)
// ---------------------------------------------------------------------------
__global__ __launch_bounds__(256) void loss_kernel(
        const u16* __restrict__ nodes, const int* __restrict__ bill,
        const int* __restrict__ u1, const int* __restrict__ u2,
        const float* __restrict__ w1, const float* __restrict__ b1,
        const float* __restrict__ w2, const float* __restrict__ b2,
        float* __restrict__ out) {
    __shared__ float Wl[128 * 64];
    __shared__ float red[2][4];
    for (int j = threadIdx.x; j < 128 * 16; j += 256)
        ((float4*)Wl)[j] = ((const float4*)w1)[j];
    __syncthreads();

    const int lane = threadIdx.x & 63;
    const int wv   = threadIdx.x >> 6;
    const int gw   = blockIdx.x * 4 + wv;
    const int nw   = gridDim.x * 4;

    const float bias1 = b1[lane];
    const float w2l   = w2[lane];
    const float bias2 = b2[0];

    float bce_acc = 0.f, corr_acc = 0.f;
    for (int s = gw; s < BATCH; s += nw) {
        const u16* xb  = nodes + (size_t)bill[s] * 64;
        const u16* xu1 = nodes + (size_t)u1[s] * 64;
        const u16* xu2 = nodes + (size_t)u2[s] * 64;
        float hb = bias1, h1 = 0.f, h2 = 0.f;
#pragma unroll 8
        for (int i = 0; i < 64; ++i) {
            float wb = Wl[i * 64 + lane];
            float wu = Wl[(64 + i) * 64 + lane];
            hb += bf2f(xb[i]) * wb;
            h1 += bf2f(xu1[i]) * wu;
            h2 += bf2f(xu2[i]) * wu;
        }
        float p1 = fmaxf(hb + h1, 0.f) * w2l;
        float p2 = fmaxf(hb + h2, 0.f) * w2l;
#pragma unroll
        for (int off = 32; off > 0; off >>= 1) {
            p1 += __shfl_down(p1, off);
            p2 += __shfl_down(p2, off);
        }
        if (lane == 0) {
            float z1 = p1 + bias2;   // target 1
            float z2 = p2 + bias2;   // target 0
            bce_acc += fmaxf(z1, 0.f) - z1 + log1pf(expf(-fabsf(z1)));
            bce_acc += fmaxf(z2, 0.f)      + log1pf(expf(-fabsf(z2)));
            corr_acc += (z1 > 0.f) ? 1.f : 0.f;
            corr_acc += (z2 > 0.f) ? 0.f : 1.f;
        }
    }
    if (lane == 0) { red[0][wv] = bce_acc; red[1][wv] = corr_acc; }
    __syncthreads();
    if (threadIdx.x == 0) {
        const float scale = 1.f / (2.f * BATCH);
        atomicAdd(&out[0], (red[0][0] + red[0][1] + red[0][2] + red[0][3]) * scale);
        atomicAdd(&out[1], (red[1][0] + red[1][1] + red[1][2] + red[1][3]) * scale);
    }
}

// ---------------------------------------------------------------------------
extern "C" void kernel_launch(void* const* d_in, const int* in_sizes, int n_in,
                              void* d_out, int out_size, void* d_ws, size_t ws_size,
                              hipStream_t stream) {
    const int*   bill  = (const int*)d_in[0];
    const int*   u1    = (const int*)d_in[1];
    const int*   u2    = (const int*)d_in[2];
    const int*   ei    = (const int*)d_in[3];
    const int*   et    = (const int*)d_in[4];
    const float* uf    = (const float*)d_in[5];
    const float* W1    = (const float*)d_in[6];
    const float* root1 = (const float*)d_in[7];
    const float* b1    = (const float*)d_in[8];
    const float* W2    = (const float*)d_in[9];
    const float* root2 = (const float*)d_in[10];
    const float* b2    = (const float*)d_in[11];
    const float* m1w   = (const float*)d_in[12];
    const float* m1b   = (const float*)d_in[13];
    const float* m2w   = (const float*)d_in[14];
    const float* m2b   = (const float*)d_in[15];
    float* out = (float*)d_out;

    // ws layout (peak 105,452,816 B < proven 106,400,000 B):
    //   0           h_all     76,800,000   [100000][384] bf16
    //  76,800,000   sorted    12,800,000   u32 gather element-offsets
    //  89,600,000   bucketed  12,800,000   u32 keys, bucket order (dead after
    //                                      seg_sort; xbuf aliases here)
    // 102,400,000   hist         800,768   [256][782] int
    // 103,200,768   btot           3,128
    // 103,203,896   boffs          3,132   (783 ints)
    // 103,207,040   offs       2,000,004   (NSEG+1 ints)
    // 105,207,056   BT1          196,608
    // 105,403,664   BT2           49,152
    char* ws = (char*)d_ws;
    u16* h_all    = (u16*)(ws);
    u32* sorted   = (u32*)(ws + 76800000);
    u32* bucketed = (u32*)(ws + 89600000);
    u16* xbuf     = (u16*)(ws + 89600000);   // alias: valid after seg_sort
    int* hist     = (int*)(ws + 102400000);
    int* btot     = (int*)(ws + 103200768);
    int* boffs    = (int*)(ws + 103203896);
    int* offs     = (int*)(ws + 103207040);
    u16* BT1      = (u16*)(ws + 105207056);
    u16* BT2      = (u16*)(ws + 105403664);
    if (ws_size < 105452816) return;  // fail visibly

    const int* src = ei;
    const int* dst = ei + N_EDGES;

    hipMemsetAsync(d_out, 0, 2 * sizeof(float), stream);

    // ---- two-level bucket sort into (dst,rel) segment order
    bucket_hist<<<NWG1, 256, 0, stream>>>(dst, hist);
    col_scan<<<NB, 64, 0, stream>>>(hist, btot);
    btot_scan<<<1, 64, 0, stream>>>(btot, boffs, offs);
    bucket_scatter<<<NWG1, 256, 0, stream>>>(src, dst, et, hist, boffs, bucketed);
    seg_sort<<<NB, 256, 0, stream>>>(bucketed, boffs, offs, sorted);

    // ---- pack weights to BT (bf16, [384][K])
    build_bt<<<(384 * EMB + 255) / 256, 256, 0, stream>>>(W1, root1, EMB, BT1);
    build_bt<<<(384 * HID + 255) / 256, 256, 0, stream>>>(W2, root2, HID, BT2);

    // ---- Layer 1
    mfma_gemm<EMB, true><<<dim3(782, 3), 256, 0, stream>>>(uf, BT1, h_all);
    agg_rl<true><<<25000, 256, 0, stream>>>(h_all, sorted, offs, b1, xbuf);

    // ---- Layer 2
    mfma_gemm<HID, false><<<dim3(782, 3), 256, 0, stream>>>(xbuf, BT2, h_all);
    agg_rl<false><<<25000, 256, 0, stream>>>(h_all, sorted, offs, b2, xbuf);

    // ---- Merge MLP + BCE + accuracy
    loss_kernel<<<128, 256, 0, stream>>>(xbuf, bill, u1, u2, m1w, m1b, m2w, m2b, out);
}

// Round 9
// 371.344 us; speedup vs baseline: 8.1680x; 1.1175x over previous
//
#include <hip/hip_runtime.h>
#include <hip/hip_bf16.h>

#define N_NODES 100000
#define EMB 256
#define HID 64
#define N_REL 5
#define N_EDGES 3200000
#define BATCH 16384
#define NB 782                 // buckets of 128 dst nodes
#define NWG1 256               // scatter/hist WGs
#define CH 12500               // edges per WG chunk (256*12500 = 3.2M exact)
#define LSEG 640               // 128 nodes * 5 rels
#define NSEG (N_NODES * N_REL) // 500000

typedef unsigned short u16;
typedef unsigned int u32;
typedef __attribute__((ext_vector_type(4))) float f32x4;
typedef __attribute__((ext_vector_type(8))) short short8;

__device__ __forceinline__ float bf2f(u16 u) {
    union { float f; u32 i; } v;
    v.i = ((u32)u) << 16;
    return v.f;
}
__device__ __forceinline__ u16 f2bf(float f) {
    union { float f; u32 i; } v;
    v.f = f;
    u32 r = v.i + 0x7fff + ((v.i >> 16) & 1);   // RNE
    return (u16)(r >> 16);
}

__device__ __forceinline__ void gload_lds16(const void* g, void* l) {
    __builtin_amdgcn_global_load_lds(
        (const __attribute__((address_space(1))) unsigned int*)g,
        (__attribute__((address_space(3))) unsigned int*)l, 16, 0, 0);
}

// ---------------------------------------------------------------------------
// K1: per-WG bucket histogram (deterministic chunks, no global atomics)
// ---------------------------------------------------------------------------
__global__ __launch_bounds__(256) void bucket_hist(const int* __restrict__ dst,
                                                   int* __restrict__ hist) {
    __shared__ int hl[NB];
    const int tid = threadIdx.x;
    for (int i = tid; i < NB; i += 256) hl[i] = 0;
    __syncthreads();
    const int w = blockIdx.x;
    const int s = w * CH, e = s + CH;
    for (int i = s + tid; i < e; i += 256)
        atomicAdd(&hl[dst[i] >> 7], 1);
    __syncthreads();
    for (int i = tid; i < NB; i += 256) hist[w * NB + i] = hl[i];
}

// ---------------------------------------------------------------------------
// K2a: per-bucket column scan over WGs (in-place hist -> base_local), btot out
// ---------------------------------------------------------------------------
__global__ void col_scan(int* __restrict__ hist, int* __restrict__ btot) {
    const int b = blockIdx.x;
    const int lane = threadIdx.x;
    int carry = 0;
    for (int c = 0; c < NWG1; c += 64) {
        int v = hist[(c + lane) * NB + b];
        int incl = v;
#pragma unroll
        for (int off = 1; off < 64; off <<= 1) {
            int t = __shfl_up(incl, off);
            if (lane >= off) incl += t;
        }
        hist[(c + lane) * NB + b] = carry + (incl - v);
        carry += __shfl(incl, 63);
    }
    if (lane == 0) btot[b] = carry;
}

// ---------------------------------------------------------------------------
// K2b: scan bucket totals -> bucket offsets (+ sentinels)
// ---------------------------------------------------------------------------
__global__ void btot_scan(const int* __restrict__ btot, int* __restrict__ boffs,
                          int* __restrict__ offs) {
    const int lane = threadIdx.x;
    int carry = 0;
    for (int c = 0; c < NB; c += 64) {
        int v = (c + lane < NB) ? btot[c + lane] : 0;
        int incl = v;
#pragma unroll
        for (int off = 1; off < 64; off <<= 1) {
            int t = __shfl_up(incl, off);
            if (lane >= off) incl += t;
        }
        if (c + lane < NB) boffs[c + lane] = carry + (incl - v);
        carry += __shfl(incl, 63);
    }
    if (lane == 0) {
        boffs[NB] = N_EDGES;
        offs[NSEG] = N_EDGES;   // global sentinel for offs-diff degree
    }
}

// ---------------------------------------------------------------------------
// K3: scatter packed keys into bucket-ordered array (LDS cursors -> bursts)
// key = src | ((ldst*5 + et) << 17)
// ---------------------------------------------------------------------------
__global__ __launch_bounds__(256) void bucket_scatter(
        const int* __restrict__ src, const int* __restrict__ dst,
        const int* __restrict__ et, const int* __restrict__ base,
        const int* __restrict__ boffs, u32* __restrict__ bucketed) {
    __shared__ int cur[NB];
    const int tid = threadIdx.x;
    const int w = blockIdx.x;
    for (int i = tid; i < NB; i += 256) cur[i] = boffs[i] + base[w * NB + i];
    __syncthreads();
    const int s = w * CH, e = s + CH;
    for (int i = s + tid; i < e; i += 256) {
        int d = dst[i];
        int b = d >> 7;
        u32 key = (u32)src[i] | ((u32)((d & 127) * 5 + et[i]) << 17);
        int pos = atomicAdd(&cur[b], 1);
        bucketed[pos] = key;
    }
}

// ---------------------------------------------------------------------------
// K4: within-bucket segment sort. One WG per bucket: LDS histogram of 640
// local segs -> wave scan -> global offs + LDS-cursor scatter.
// Output = precomputed gather ELEMENT offset: src*384 + rel*64 (fits u32).
// ---------------------------------------------------------------------------
__global__ __launch_bounds__(256) void seg_sort(
        const u32* __restrict__ keys, const int* __restrict__ boffs,
        int* __restrict__ offs, u32* __restrict__ soff) {
    __shared__ int cntl[LSEG];
    __shared__ int cur[LSEG];
    const int tid = threadIdx.x;
    const int b = blockIdx.x;
    const int s = boffs[b], e = boffs[b + 1];

    for (int i = tid; i < LSEG; i += 256) cntl[i] = 0;
    __syncthreads();
    for (int i = s + tid; i < e; i += 256)
        atomicAdd(&cntl[keys[i] >> 17], 1);
    __syncthreads();

    if (tid < 64) {   // wave 0: exclusive scan of 640 counts
        int carry = 0;
        for (int c = 0; c < LSEG; c += 64) {
            int v = cntl[c + tid];
            int incl = v;
#pragma unroll
            for (int off = 1; off < 64; off <<= 1) {
                int t = __shfl_up(incl, off);
                if (tid >= off) incl += t;
            }
            cur[c + tid] = carry + (incl - v);
            carry += __shfl(incl, 63);
        }
    }
    __syncthreads();

    const int segbase = b * LSEG;   // == (b*128)*5
    for (int i = tid; i < LSEG; i += 256)
        if (segbase + i < NSEG) offs[segbase + i] = s + cur[i];
    __syncthreads();

    for (int i = s + tid; i < e; i += 256) {
        u32 key = keys[i];
        u32 lseg = key >> 17;
        int pos = s + atomicAdd(&cur[lseg], 1);
        u32 q = (lseg * 52429u) >> 18;          // lseg / 5
        u32 rel = lseg - q * 5u;
        soff[pos] = (key & 0x1FFFF) * 384u + rel * 64u;
    }
}

// ---------------------------------------------------------------------------
// Pack weights: BT[j][k] = (j<320 ? W[j>>6][k][j&63] : root[k][j&63]) as bf16
// ---------------------------------------------------------------------------
__global__ void build_bt(const float* __restrict__ W, const float* __restrict__ root,
                         int K, u16* __restrict__ BT) {
    int idx = blockIdx.x * blockDim.x + threadIdx.x;
    if (idx >= 384 * K) return;
    int j = idx / K, k = idx - j * K;
    float v = (j < 320) ? W[((j >> 6) * K + k) * 64 + (j & 63)]
                        : root[k * 64 + (j & 63)];
    BT[idx] = f2bf(v);
}

// ---------------------------------------------------------------------------
// MFMA GEMM: C[100000][384](bf16) = A[100000][K] x BT[384][K]^T
// (unchanged — verified correct)
// ---------------------------------------------------------------------------
template <int K, bool A_F32>
__global__ __launch_bounds__(256) void mfma_gemm(
        const void* __restrict__ Av, const u16* __restrict__ BT,
        u16* __restrict__ C) {
    __shared__ __align__(16) u16 Al[128 * 64];
    __shared__ __align__(16) u16 Bl[128 * 64];
    const int tid  = threadIdx.x;
    const int lane = tid & 63;
    const int wave = tid >> 6;
    const int m0 = blockIdx.x * 128;
    const int n0 = blockIdx.y * 128;
    const int wr = (wave >> 1) * 64;
    const int wc = (wave & 1) * 64;
    const int l15 = lane & 15;
    const int lg  = lane >> 4;

    f32x4 acc[4][4];
#pragma unroll
    for (int i = 0; i < 4; ++i)
#pragma unroll
        for (int j = 0; j < 4; ++j) {
            f32x4 z = {0.f, 0.f, 0.f, 0.f};
            acc[i][j] = z;
        }

    for (int k0 = 0; k0 < K; k0 += 64) {
#pragma unroll
        for (int i = 0; i < 4; ++i) {
            int c = wave * 4 + i;
            int row = c * 8 + (lane >> 3);
            int kk  = (lane & 7) * 8;
            gload_lds16(BT + (size_t)(n0 + row) * K + k0 + kk, &Bl[c * 512]);
        }
        if (A_F32) {
            const float* Af = (const float*)Av;
#pragma unroll
            for (int p = 0; p < 8; ++p) {
                int f = p * 1024 + tid * 4;
                int row = f >> 6;
                int col = f & 63;
                int gr = m0 + row;
                if (gr > N_NODES - 1) gr = N_NODES - 1;
                float4 v = *(const float4*)(Af + (size_t)gr * K + k0 + col);
                ushort4 o;
                o.x = f2bf(v.x); o.y = f2bf(v.y); o.z = f2bf(v.z); o.w = f2bf(v.w);
                *(ushort4*)&Al[row * 64 + col] = o;
            }
        } else {
            const u16* Ab = (const u16*)Av;
#pragma unroll
            for (int i = 0; i < 4; ++i) {
                int c = wave * 4 + i;
                int row = c * 8 + (lane >> 3);
                int kk  = (lane & 7) * 8;
                gload_lds16(Ab + (size_t)(m0 + row) * K + k0 + kk, &Al[c * 512]);
            }
        }
        __syncthreads();

#pragma unroll
        for (int kk = 0; kk < 64; kk += 32) {
            short8 af[4], bf[4];
#pragma unroll
            for (int f = 0; f < 4; ++f) {
                af[f] = *(const short8*)&Al[(wr + f * 16 + l15) * 64 + kk + lg * 8];
                bf[f] = *(const short8*)&Bl[(wc + f * 16 + l15) * 64 + kk + lg * 8];
            }
#pragma unroll
            for (int fm = 0; fm < 4; ++fm)
#pragma unroll
                for (int fn = 0; fn < 4; ++fn)
                    acc[fm][fn] = __builtin_amdgcn_mfma_f32_16x16x32_bf16(
                        af[fm], bf[fn], acc[fm][fn], 0, 0, 0);
        }
        __syncthreads();
    }

#pragma unroll
    for (int fm = 0; fm < 4; ++fm) {
        int rbase = m0 + wr + fm * 16 + lg * 4;
#pragma unroll
        for (int i = 0; i < 4; ++i) {
            int r = rbase + i;
            if (r < N_NODES) {
#pragma unroll
                for (int fn = 0; fn < 4; ++fn)
                    C[(size_t)r * 384 + n0 + wc + fn * 16 + l15] = f2bf(acc[fm][fn][i]);
            }
        }
    }
}

// ---------------------------------------------------------------------------
// Aggregate (readlane): one wave per dst node, lane = feature.
// Per 64-edge chunk: ONE coalesced load of 64 offsets + per-lane weight;
// inner loop broadcasts offset/weight via v_readlane (SGPR) so the gather is
// SGPR-base + lane*2 and loads issue back-to-back (no scalar-load chain).
// Tail edges get weight 0 with clamped offsets -> no inner-loop guards.
// ---------------------------------------------------------------------------
template <bool RELU>
__global__ __launch_bounds__(256) void agg_rl(
        const u16* __restrict__ h, const u32* __restrict__ soff,
        const int* __restrict__ offs, const float* __restrict__ bias,
        u16* __restrict__ out) {
    const int lane = threadIdx.x & 63;
    const int d = (blockIdx.x * blockDim.x + threadIdx.x) >> 6;
    if (d >= N_NODES) return;

    const int o0 = offs[d * 5 + 0], o1 = offs[d * 5 + 1], o2 = offs[d * 5 + 2];
    const int o3 = offs[d * 5 + 3], o4 = offs[d * 5 + 4], o5 = offs[d * 5 + 5];
    const float i0 = 1.f / (float)max(o1 - o0, 1);
    const float i1 = 1.f / (float)max(o2 - o1, 1);
    const float i2 = 1.f / (float)max(o3 - o2, 1);
    const float i3 = 1.f / (float)max(o4 - o3, 1);
    const float i4 = 1.f / (float)max(o5 - o4, 1);

    const u16* hl = h + lane;
    float acc0 = bf2f(h[(size_t)d * 384 + 320 + lane]) + bias[lane];
    float acc1 = 0.f;

    for (int base = o0; base < o5; base += 64) {
        const int idx = base + lane;
        const u32 voff = soff[min(idx, o5 - 1)];          // coalesced, clamped
        float wv = idx < o1 ? i0 : idx < o2 ? i1 : idx < o3 ? i2
                 : idx < o4 ? i3 : i4;
        if (idx >= o5) wv = 0.f;                          // tail contributes 0
        const int m = min(64, o5 - base);
        for (int j = 0; j < m; j += 8) {
#pragma unroll
            for (int jj = 0; jj < 8; jj += 2) {
                int  offa = __builtin_amdgcn_readlane((int)voff, j + jj);
                int  wa_i = __builtin_amdgcn_readlane((int)__float_as_uint(wv), j + jj);
                int  offb = __builtin_amdgcn_readlane((int)voff, j + jj + 1);
                int  wb_i = __builtin_amdgcn_readlane((int)__float_as_uint(wv), j + jj + 1);
                acc0 += bf2f(hl[(u32)offa]) * __uint_as_float((u32)wa_i);
                acc1 += bf2f(hl[(u32)offb]) * __uint_as_float((u32)wb_i);
            }
        }
    }
    float acc = acc0 + acc1;
    if (RELU) acc = fmaxf(acc, 0.f);
    out[(size_t)d * 64 + lane] = f2bf(acc);
}

// ---------------------------------------------------------------------------
// Merge MLP + BCE/accuracy (nodes in bf16)
// 1024 blocks (16 waves/CU with 33KB LDS) -> latency-hiding occupancy.
// ---------------------------------------------------------------------------
__global__ __launch_bounds__(256) void loss_kernel(
        const u16* __restrict__ nodes, const int* __restrict__ bill,
        const int* __restrict__ u1, const int* __restrict__ u2,
        const float* __restrict__ w1, const float* __restrict__ b1,
        const float* __restrict__ w2, const float* __restrict__ b2,
        float* __restrict__ out) {
    __shared__ float Wl[128 * 64];
    __shared__ float red[2][4];
    for (int j = threadIdx.x; j < 128 * 16; j += 256)
        ((float4*)Wl)[j] = ((const float4*)w1)[j];
    __syncthreads();

    const int lane = threadIdx.x & 63;
    const int wv   = threadIdx.x >> 6;
    const int gw   = blockIdx.x * 4 + wv;
    const int nw   = gridDim.x * 4;

    const float bias1 = b1[lane];
    const float w2l   = w2[lane];
    const float bias2 = b2[0];

    float bce_acc = 0.f, corr_acc = 0.f;
    for (int s = gw; s < BATCH; s += nw) {
        const u16* xb  = nodes + (size_t)bill[s] * 64;
        const u16* xu1 = nodes + (size_t)u1[s] * 64;
        const u16* xu2 = nodes + (size_t)u2[s] * 64;
        float hb = bias1, h1 = 0.f, h2 = 0.f;
#pragma unroll 8
        for (int i = 0; i < 64; ++i) {
            float wb = Wl[i * 64 + lane];
            float wu = Wl[(64 + i) * 64 + lane];
            hb += bf2f(xb[i]) * wb;
            h1 += bf2f(xu1[i]) * wu;
            h2 += bf2f(xu2[i]) * wu;
        }
        float p1 = fmaxf(hb + h1, 0.f) * w2l;
        float p2 = fmaxf(hb + h2, 0.f) * w2l;
#pragma unroll
        for (int off = 32; off > 0; off >>= 1) {
            p1 += __shfl_down(p1, off);
            p2 += __shfl_down(p2, off);
        }
        if (lane == 0) {
            float z1 = p1 + bias2;   // target 1
            float z2 = p2 + bias2;   // target 0
            bce_acc += fmaxf(z1, 0.f) - z1 + log1pf(expf(-fabsf(z1)));
            bce_acc += fmaxf(z2, 0.f)      + log1pf(expf(-fabsf(z2)));
            corr_acc += (z1 > 0.f) ? 1.f : 0.f;
            corr_acc += (z2 > 0.f) ? 0.f : 1.f;
        }
    }
    if (lane == 0) { red[0][wv] = bce_acc; red[1][wv] = corr_acc; }
    __syncthreads();
    if (threadIdx.x == 0) {
        const float scale = 1.f / (2.f * BATCH);
        atomicAdd(&out[0], (red[0][0] + red[0][1] + red[0][2] + red[0][3]) * scale);
        atomicAdd(&out[1], (red[1][0] + red[1][1] + red[1][2] + red[1][3]) * scale);
    }
}

// ---------------------------------------------------------------------------
extern "C" void kernel_launch(void* const* d_in, const int* in_sizes, int n_in,
                              void* d_out, int out_size, void* d_ws, size_t ws_size,
                              hipStream_t stream) {
    const int*   bill  = (const int*)d_in[0];
    const int*   u1    = (const int*)d_in[1];
    const int*   u2    = (const int*)d_in[2];
    const int*   ei    = (const int*)d_in[3];
    const int*   et    = (const int*)d_in[4];
    const float* uf    = (const float*)d_in[5];
    const float* W1    = (const float*)d_in[6];
    const float* root1 = (const float*)d_in[7];
    const float* b1    = (const float*)d_in[8];
    const float* W2    = (const float*)d_in[9];
    const float* root2 = (const float*)d_in[10];
    const float* b2    = (const float*)d_in[11];
    const float* m1w   = (const float*)d_in[12];
    const float* m1b   = (const float*)d_in[13];
    const float* m2w   = (const float*)d_in[14];
    const float* m2b   = (const float*)d_in[15];
    float* out = (float*)d_out;

    // ws layout (peak 105,452,816 B < proven 106,400,000 B):
    //   0           h_all     76,800,000   [100000][384] bf16
    //  76,800,000   sorted    12,800,000   u32 gather element-offsets
    //  89,600,000   bucketed  12,800,000   u32 keys, bucket order (dead after
    //                                      seg_sort; xbuf aliases here)
    // 102,400,000   hist         800,768   [256][782] int
    // 103,200,768   btot           3,128
    // 103,203,896   boffs          3,132   (783 ints)
    // 103,207,040   offs       2,000,004   (NSEG+1 ints)
    // 105,207,056   BT1          196,608
    // 105,403,664   BT2           49,152
    char* ws = (char*)d_ws;
    u16* h_all    = (u16*)(ws);
    u32* sorted   = (u32*)(ws + 76800000);
    u32* bucketed = (u32*)(ws + 89600000);
    u16* xbuf     = (u16*)(ws + 89600000);   // alias: valid after seg_sort
    int* hist     = (int*)(ws + 102400000);
    int* btot     = (int*)(ws + 103200768);
    int* boffs    = (int*)(ws + 103203896);
    int* offs     = (int*)(ws + 103207040);
    u16* BT1      = (u16*)(ws + 105207056);
    u16* BT2      = (u16*)(ws + 105403664);
    if (ws_size < 105452816) return;  // fail visibly

    const int* src = ei;
    const int* dst = ei + N_EDGES;

    hipMemsetAsync(d_out, 0, 2 * sizeof(float), stream);

    // ---- two-level bucket sort into (dst,rel) segment order
    bucket_hist<<<NWG1, 256, 0, stream>>>(dst, hist);
    col_scan<<<NB, 64, 0, stream>>>(hist, btot);
    btot_scan<<<1, 64, 0, stream>>>(btot, boffs, offs);
    bucket_scatter<<<NWG1, 256, 0, stream>>>(src, dst, et, hist, boffs, bucketed);
    seg_sort<<<NB, 256, 0, stream>>>(bucketed, boffs, offs, sorted);

    // ---- pack weights to BT (bf16, [384][K])
    build_bt<<<(384 * EMB + 255) / 256, 256, 0, stream>>>(W1, root1, EMB, BT1);
    build_bt<<<(384 * HID + 255) / 256, 256, 0, stream>>>(W2, root2, HID, BT2);

    // ---- Layer 1
    mfma_gemm<EMB, true><<<dim3(782, 3), 256, 0, stream>>>(uf, BT1, h_all);
    agg_rl<true><<<25000, 256, 0, stream>>>(h_all, sorted, offs, b1, xbuf);

    // ---- Layer 2
    mfma_gemm<HID, false><<<dim3(782, 3), 256, 0, stream>>>(xbuf, BT2, h_all);
    agg_rl<false><<<25000, 256, 0, stream>>>(h_all, sorted, offs, b2, xbuf);

    // ---- Merge MLP + BCE + accuracy
    loss_kernel<<<1024, 256, 0, stream>>>(xbuf, bill, u1, u2, m1w, m1b, m2w, m2b, out);
}